// Round 6
// baseline (465.882 us; speedup 1.0000x reference)
//
#include <hip/hip_runtime.h>
#include <math.h>

#define NN 8192
#define DIN 256
#define DOUT 128
#define HS 8208      // hT row stride (bf16 elems), 16416 B (16B-aligned)
#define PSTRIDE 136  // p_lds row stride (bf16 elems) = 272 B: 16B-multiple, bank-spread

// Raw barrier WITHOUT the vmcnt(0) drain __syncthreads() emits: only LDS
// (lgkmcnt) must be visible across the barrier; global prefetches stay in
// flight and are waited via counted vmcnt at their register use.
#define BAR_LDS() do { asm volatile("s_waitcnt lgkmcnt(0)" ::: "memory"); \
                       __builtin_amdgcn_s_barrier(); } while (0)

typedef __attribute__((ext_vector_type(8))) short short8;
typedef __attribute__((ext_vector_type(8))) __bf16 bf16x8;
typedef __attribute__((ext_vector_type(4))) float f32x4;
typedef __attribute__((ext_vector_type(4))) unsigned short ushort4v;
typedef __attribute__((ext_vector_type(4))) unsigned int uint4v;
typedef __attribute__((ext_vector_type(4))) int int4v;

__device__ __forceinline__ bf16x8 as_bf(short8 s) { return __builtin_bit_cast(bf16x8, s); }
__device__ __forceinline__ unsigned short f2bf(float f) {
  union { float ff; unsigned int i; } v; v.ff = f;
  unsigned int r = v.i + 0x7FFFu + ((v.i >> 16) & 1u);
  return (unsigned short)(r >> 16);
}

// ---- Kernel 0: one-time W -> bf16 conversion + a2key init --------------------
__global__ __launch_bounds__(256) void k0_prep(const float* __restrict__ W,
                                               unsigned short* __restrict__ Wbf,
                                               unsigned int* __restrict__ a2key)
{
  const int i = (blockIdx.x * 256 + threadIdx.x) * 4;   // 32 blocks cover 32768 elems
  f32x4 v = *(const f32x4*)(W + i);
  ushort4v o;
#pragma unroll
  for (int t = 0; t < 4; ++t) o[t] = f2bf(v[t]);
  *(ushort4v*)(Wbf + i) = o;
  if (blockIdx.x == 0 && threadIdx.x == 0) *a2key = 0u;  // keys are always > 0
}

// ---- Kernel 1 (MFMA): hT (bf16, [d][j] padded); a1, a2; global max(a2) ------
// grid 512 x block 64 (1 wave): 16 rows x 128 dims via 8 C-frags of 16x16x32.
// Verified layout: A[m=lane&15][k=q*8+t]; B[k=q*8+t][n=lane&15]; D: col=lane&15, row=q*4+reg.
__global__ __launch_bounds__(64) void k1_h(
    const float* __restrict__ feat, const unsigned short* __restrict__ Wbf,
    const float* __restrict__ bias, const float* __restrict__ w1,
    const float* __restrict__ b1, const float* __restrict__ w2,
    const float* __restrict__ b2,
    unsigned short* __restrict__ hT,
    float* __restrict__ a1, float* __restrict__ a2,
    unsigned int* __restrict__ a2key)
{
  const int lane = threadIdx.x;
  const int m = lane & 15, q = lane >> 4;
  const int r0 = blockIdx.x * 16;

  f32x4 acc[8] = {};
  const float* fRow = feat + (size_t)(r0 + m) * DIN + q * 8;
#pragma unroll
  for (int k0 = 0; k0 < DIN; k0 += 32) {
    short8 af;
#pragma unroll
    for (int t = 0; t < 8; ++t) af[t] = (short)f2bf(fRow[k0 + t]);
#pragma unroll
    for (int g = 0; g < 8; ++g) {
      const short8 wf = *(const short8*)(Wbf + (size_t)(g * 16 + m) * DIN + k0 + q * 8);
      acc[g] = __builtin_amdgcn_mfma_f32_16x16x32_bf16(as_bf(af), as_bf(wf), acc[g], 0, 0, 0);
    }
  }
  float s1[4] = {0.f, 0.f, 0.f, 0.f}, s2[4] = {0.f, 0.f, 0.f, 0.f};
#pragma unroll
  for (int g = 0; g < 8; ++g) {
    const int d = g * 16 + m;
    const float bv = bias[d];
    const float w1v = w1[d];
    const float w2v = w2[d];
    ushort4v st;
#pragma unroll
    for (int r = 0; r < 4; ++r) {
      float v = acc[g][r] + bv;
      st[r] = f2bf(v);
      s1[r] += v * w1v;
      s2[r] += v * w2v;
    }
    *(ushort4v*)(hT + (size_t)d * HS + r0 + q * 4) = st;  // bf16 hT for k2 B-frags
  }
#pragma unroll
  for (int r = 0; r < 4; ++r) {
    s1[r] += __shfl_xor(s1[r], 1, 64); s2[r] += __shfl_xor(s2[r], 1, 64);
    s1[r] += __shfl_xor(s1[r], 2, 64); s2[r] += __shfl_xor(s2[r], 2, 64);
    s1[r] += __shfl_xor(s1[r], 4, 64); s2[r] += __shfl_xor(s2[r], 4, 64);
    s1[r] += __shfl_xor(s1[r], 8, 64); s2[r] += __shfl_xor(s2[r], 8, 64);
  }
  const float bb1 = b1[0], bb2 = b2[0];
  if (m == 0) {
#pragma unroll
    for (int r = 0; r < 4; ++r) {
      a1[r0 + q * 4 + r] = s1[r] + bb1;
      a2[r0 + q * 4 + r] = s2[r] + bb2;
    }
  }
  float am = fmaxf(fmaxf(s2[0], s2[1]), fmaxf(s2[2], s2[3])) + bb2;
  am = fmaxf(am, __shfl_xor(am, 16, 64));
  am = fmaxf(am, __shfl_xor(am, 32, 64));
  if (lane == 0) {
    unsigned int u = __float_as_uint(am);
    unsigned int key = (u & 0x80000000u) ? ~u : (u | 0x80000000u);  // order-preserving
    atomicMax(a2key, key);
  }
}

// exp + pack 8 p-values: 4x v_cvt_pk_bf16_f32 (RNE, same rounding as f2bf)
__device__ __forceinline__ short8 expify8(int4v d0, int4v d1, f32x4 v0, f32x4 v1,
                                          float a1i, float mi, float& z)
{
  float p[8];
#pragma unroll
  for (int t = 0; t < 4; ++t) {
    float y = a1i + v0[t];
    float ly = fmaxf(y, 0.01f * y);
    float pv = (d0[t] > 0) ? __expf(ly - mi) : 0.f;
    z += pv;
    p[t] = pv;
  }
#pragma unroll
  for (int t = 0; t < 4; ++t) {
    float y = a1i + v1[t];
    float ly = fmaxf(y, 0.01f * y);
    float pv = (d1[t] > 0) ? __expf(ly - mi) : 0.f;
    z += pv;
    p[4 + t] = pv;
  }
  uint4v u;
  asm("v_cvt_pk_bf16_f32 %0, %1, %2" : "=v"(u[0]) : "v"(p[0]), "v"(p[1]));
  asm("v_cvt_pk_bf16_f32 %0, %1, %2" : "=v"(u[1]) : "v"(p[2]), "v"(p[3]));
  asm("v_cvt_pk_bf16_f32 %0, %1, %2" : "=v"(u[2]) : "v"(p[4]), "v"(p[5]));
  asm("v_cvt_pk_bf16_f32 %0, %1, %2" : "=v"(u[3]) : "v"(p[6]), "v"(p[7]));
  return __builtin_bit_cast(short8, u);
}

// ---- Kernel 2 (MFMA, distance-2 prefetch, counted-wait barriers) -------------
// Block: 16 rows x 128 d, 256 thr (4 waves). Wave w owns d-tiles {w*32, w*32+16}.
// Two named pending sets (A/B) + 2x-unrolled tile loop: adj/a2 for tile t are
// issued TWO tile bodies before their expify (~1300+ cyc > ~900 cyc HBM
// latency), so the steady-state vmcnt wait at expify is ~0. Barriers do not
// drain vmcnt (BAR_LDS), so prefetches genuinely span them.
__global__ __launch_bounds__(256) void GATLayer_46024869544127_kernel(
    const int* __restrict__ adj, const unsigned short* __restrict__ hT,
    const float* __restrict__ a1, const float* __restrict__ a2,
    const unsigned int* __restrict__ a2key, float* __restrict__ out)
{
  __shared__ unsigned short p_lds[2][16][PSTRIDE];
  __shared__ float zred[4][16];

  const int tid = threadIdx.x;
  const int lane = tid & 63;
  const int w = tid >> 6;                 // wave 0..3
  const int r0 = blockIdx.x * 16;
  const int NT = NN / 128;                // 64 (even -> clean 2x unroll)

  // phase-A mapping: thread -> (row, 8-j group)
  const int arow = tid & 15;
  const int ajg = tid >> 4;
  const float a1i = a1[r0 + arow];
  const unsigned int kraw = *a2key;
  const unsigned int mu = (kraw & 0x80000000u) ? (kraw ^ 0x80000000u) : ~kraw;
  const float yi = a1i + __uint_as_float(mu);
  const float mi = fmaxf(yi, 0.01f * yi);   // leaky is monotonic -> valid shift

  float zpart = 0.f;
  const int* adjRow = adj + (size_t)(r0 + arow) * NN + ajg * 8;
  const float* a2p = a2 + ajg * 8;

  // phase-B mapping
  const int m = lane & 15, q = lane >> 4;
  const int d0 = w * 32;
  const unsigned short* hT0 = hT + (size_t)(d0 + m) * HS + q * 8;
  const unsigned short* hT1 = hT + (size_t)(d0 + 16 + m) * HS + q * 8;

  f32x4 acc0 = {}, acc1 = {};

  // two pending register sets (named scalars -> VGPRs, no runtime indexing)
  int4v pAd0, pAd1, pBd0, pBd1;
  f32x4 pAv0, pAv1, pBv0, pBv1;

#define ISSUE_A(J0) do { pAd0 = *(const int4v*)(adjRow + (J0)); \
                         pAd1 = *(const int4v*)(adjRow + (J0) + 4); \
                         pAv0 = *(const f32x4*)(a2p + (J0)); \
                         pAv1 = *(const f32x4*)(a2p + (J0) + 4); } while (0)
#define ISSUE_B(J0) do { pBd0 = *(const int4v*)(adjRow + (J0)); \
                         pBd1 = *(const int4v*)(adjRow + (J0) + 4); \
                         pBv0 = *(const f32x4*)(a2p + (J0)); \
                         pBv1 = *(const f32x4*)(a2p + (J0) + 4); } while (0)

#define MFMA_TILE(CUR, J0) do { \
    const short8 b00 = *(const short8*)(hT0 + (J0)); \
    const short8 b01 = *(const short8*)(hT1 + (J0)); \
    const short8 b10 = *(const short8*)(hT0 + (J0) + 32); \
    const short8 b11 = *(const short8*)(hT1 + (J0) + 32); \
    const short8 b20 = *(const short8*)(hT0 + (J0) + 64); \
    const short8 b21 = *(const short8*)(hT1 + (J0) + 64); \
    const short8 b30 = *(const short8*)(hT0 + (J0) + 96); \
    const short8 b31 = *(const short8*)(hT1 + (J0) + 96); \
    const short8 af0 = *(const short8*)&p_lds[CUR][m][q * 8]; \
    const short8 af1 = *(const short8*)&p_lds[CUR][m][32 + q * 8]; \
    const short8 af2 = *(const short8*)&p_lds[CUR][m][64 + q * 8]; \
    const short8 af3 = *(const short8*)&p_lds[CUR][m][96 + q * 8]; \
    acc0 = __builtin_amdgcn_mfma_f32_16x16x32_bf16(as_bf(af0), as_bf(b00), acc0, 0, 0, 0); \
    acc1 = __builtin_amdgcn_mfma_f32_16x16x32_bf16(as_bf(af0), as_bf(b01), acc1, 0, 0, 0); \
    acc0 = __builtin_amdgcn_mfma_f32_16x16x32_bf16(as_bf(af1), as_bf(b10), acc0, 0, 0, 0); \
    acc1 = __builtin_amdgcn_mfma_f32_16x16x32_bf16(as_bf(af1), as_bf(b11), acc1, 0, 0, 0); \
    acc0 = __builtin_amdgcn_mfma_f32_16x16x32_bf16(as_bf(af2), as_bf(b20), acc0, 0, 0, 0); \
    acc1 = __builtin_amdgcn_mfma_f32_16x16x32_bf16(as_bf(af2), as_bf(b21), acc1, 0, 0, 0); \
    acc0 = __builtin_amdgcn_mfma_f32_16x16x32_bf16(as_bf(af3), as_bf(b30), acc0, 0, 0, 0); \
    acc1 = __builtin_amdgcn_mfma_f32_16x16x32_bf16(as_bf(af3), as_bf(b31), acc1, 0, 0, 0); \
  } while (0)

  // prologue: issue tile0 (consumed now), tile1 (set A), tile2 (set B);
  // tile0 -> LDS buf0 synchronously (one-time ramp stall only).
  {
    int4v td0 = *(const int4v*)(adjRow);
    int4v td1 = *(const int4v*)(adjRow + 4);
    f32x4 tv0 = *(const f32x4*)(a2p);
    f32x4 tv1 = *(const f32x4*)(a2p + 4);
    ISSUE_A(128);
    ISSUE_B(256);
    short8 o = expify8(td0, td1, tv0, tv1, a1i, mi, zpart);
    *(short8*)&p_lds[0][arow][ajg * 8] = o;
  }
  BAR_LDS();

  for (int jt = 0; jt < NT; jt += 2) {
    // ---- even body: compute buf0 = tile jt; prepare tile jt+1 -> buf1 ----
    {
      short8 o = expify8(pAd0, pAd1, pAv0, pAv1, a1i, mi, zpart);  // data jt+1
      if (jt + 3 < NT) ISSUE_A((jt + 3) * 128);                    // consumed @ jt+2
      MFMA_TILE(0, jt * 128);
      *(short8*)&p_lds[1][arow][ajg * 8] = o;                      // jt+1<NT always
      BAR_LDS();
    }
    // ---- odd body: compute buf1 = tile jt+1; prepare tile jt+2 -> buf0 ----
    {
      short8 o;
      const bool hasN = (jt + 2) < NT;
      if (hasN) o = expify8(pBd0, pBd1, pBv0, pBv1, a1i, mi, zpart);  // data jt+2
      if (jt + 4 < NT) ISSUE_B((jt + 4) * 128);                       // consumed @ jt+3
      MFMA_TILE(1, (jt + 1) * 128);
      if (hasN) *(short8*)&p_lds[0][arow][ajg * 8] = o;
      BAR_LDS();
    }
  }

  // Z reduction: sum zpart over the 16 j-groups for each row
  float zw = zpart;
  zw += __shfl_xor(zw, 16, 64);
  zw += __shfl_xor(zw, 32, 64);
  if (lane < 16) zred[w][arow] = zw;
  __syncthreads();

#pragma unroll
  for (int r = 0; r < 4; ++r) {
    const int row = q * 4 + r;
    const float Z = zred[0][row] + zred[1][row] + zred[2][row] + zred[3][row];
    const float inv = (Z > 0.f) ? 1.f / Z : 0.f;
    out[(size_t)(r0 + row) * DOUT + d0 + m] = acc0[r] * inv;
    out[(size_t)(r0 + row) * DOUT + d0 + 16 + m] = acc1[r] * inv;
  }
#undef ISSUE_A
#undef ISSUE_B
#undef MFMA_TILE
}

extern "C" void kernel_launch(void* const* d_in, const int* in_sizes, int n_in,
                              void* d_out, int out_size, void* d_ws, size_t ws_size,
                              hipStream_t stream) {
  const float* feat = (const float*)d_in[0];
  const int* adj = (const int*)d_in[1];
  const float* W = (const float*)d_in[2];
  const float* b = (const float*)d_in[3];
  const float* w1 = (const float*)d_in[4];
  const float* b1 = (const float*)d_in[5];
  const float* w2 = (const float*)d_in[6];
  const float* b2 = (const float*)d_in[7];
  float* out = (float*)d_out;

  char* ws = (char*)d_ws;
  unsigned short* hT = (unsigned short*)ws;                 // 128*8208*2 B = 2,101,248
  float* a1 = (float*)(ws + (size_t)DOUT * HS * 2);
  float* a2 = a1 + NN;
  unsigned int* a2key = (unsigned int*)(a2 + NN);
  unsigned short* Wbf = (unsigned short*)(a2key + 4);       // 64 KB, 16B-aligned

  k0_prep<<<DOUT * DIN / (256 * 4), 256, 0, stream>>>(W, Wbf, a2key);
  k1_h<<<512, 64, 0, stream>>>(feat, Wbf, b, w1, b1, w2, b2, hT, a1, a2, a2key);
  GATLayer_46024869544127_kernel<<<NN / 16, 256, 0, stream>>>(adj, hT, a1, a2, a2key, out);
}

// Round 9
// 445.530 us; speedup vs baseline: 1.0457x; 1.0457x over previous
//
#include <hip/hip_runtime.h>
#include <math.h>

#define NN 8192
#define DIN 256
#define DOUT 128
#define HS 8208      // hT row stride (bf16 elems), 16416 B (16B-aligned)
#define PSTRIDE 136  // p_lds row stride (bf16 elems) = 272 B: 16B-multiple, bank-spread
#define NSLICE 4     // j-dimension split factor (occupancy + serial-chain / 4)
#define JSL (NN / NSLICE)   // 2048 j per slice

// Raw barrier WITHOUT the vmcnt(0) drain __syncthreads() emits (proven correct
// rounds 5-6): only LDS visibility is needed across the tile barrier.
#define BAR_LDS() do { asm volatile("s_waitcnt lgkmcnt(0)" ::: "memory"); \
                       __builtin_amdgcn_s_barrier(); } while (0)

typedef __attribute__((ext_vector_type(8))) short short8;
typedef __attribute__((ext_vector_type(8))) __bf16 bf16x8;
typedef __attribute__((ext_vector_type(4))) float f32x4;
typedef __attribute__((ext_vector_type(4))) unsigned short ushort4v;
typedef __attribute__((ext_vector_type(4))) int int4v;

__device__ __forceinline__ bf16x8 as_bf(short8 s) { return __builtin_bit_cast(bf16x8, s); }
__device__ __forceinline__ unsigned short f2bf(float f) {
  union { float ff; unsigned int i; } v; v.ff = f;
  unsigned int r = v.i + 0x7FFFu + ((v.i >> 16) & 1u);
  return (unsigned short)(r >> 16);
}

// ---- Kernel 0: one-time W -> bf16 conversion + a2key init --------------------
__global__ __launch_bounds__(256) void k0_prep(const float* __restrict__ W,
                                               unsigned short* __restrict__ Wbf,
                                               unsigned int* __restrict__ a2key)
{
  const int i = (blockIdx.x * 256 + threadIdx.x) * 4;   // 32 blocks cover 32768 elems
  f32x4 v = *(const f32x4*)(W + i);
  ushort4v o;
#pragma unroll
  for (int t = 0; t < 4; ++t) o[t] = f2bf(v[t]);
  *(ushort4v*)(Wbf + i) = o;
  if (blockIdx.x == 0 && threadIdx.x == 0) *a2key = 0u;  // keys are always > 0
}

// ---- Kernel 1 (MFMA): hT (bf16, [d][j] padded); a1, a2; global max(a2) ------
__global__ __launch_bounds__(64) void k1_h(
    const float* __restrict__ feat, const unsigned short* __restrict__ Wbf,
    const float* __restrict__ bias, const float* __restrict__ w1,
    const float* __restrict__ b1, const float* __restrict__ w2,
    const float* __restrict__ b2,
    unsigned short* __restrict__ hT,
    float* __restrict__ a1, float* __restrict__ a2,
    unsigned int* __restrict__ a2key)
{
  const int lane = threadIdx.x;
  const int m = lane & 15, q = lane >> 4;
  const int r0 = blockIdx.x * 16;

  f32x4 acc[8] = {};
  const float* fRow = feat + (size_t)(r0 + m) * DIN + q * 8;
#pragma unroll
  for (int k0 = 0; k0 < DIN; k0 += 32) {
    short8 af;
#pragma unroll
    for (int t = 0; t < 8; ++t) af[t] = (short)f2bf(fRow[k0 + t]);
#pragma unroll
    for (int g = 0; g < 8; ++g) {
      const short8 wf = *(const short8*)(Wbf + (size_t)(g * 16 + m) * DIN + k0 + q * 8);
      acc[g] = __builtin_amdgcn_mfma_f32_16x16x32_bf16(as_bf(af), as_bf(wf), acc[g], 0, 0, 0);
    }
  }
  float s1[4] = {0.f, 0.f, 0.f, 0.f}, s2[4] = {0.f, 0.f, 0.f, 0.f};
#pragma unroll
  for (int g = 0; g < 8; ++g) {
    const int d = g * 16 + m;
    const float bv = bias[d];
    const float w1v = w1[d];
    const float w2v = w2[d];
    ushort4v st;
#pragma unroll
    for (int r = 0; r < 4; ++r) {
      float v = acc[g][r] + bv;
      st[r] = f2bf(v);
      s1[r] += v * w1v;
      s2[r] += v * w2v;
    }
    *(ushort4v*)(hT + (size_t)d * HS + r0 + q * 4) = st;  // bf16 hT for k2 B-frags
  }
#pragma unroll
  for (int r = 0; r < 4; ++r) {
    s1[r] += __shfl_xor(s1[r], 1, 64); s2[r] += __shfl_xor(s2[r], 1, 64);
    s1[r] += __shfl_xor(s1[r], 2, 64); s2[r] += __shfl_xor(s2[r], 2, 64);
    s1[r] += __shfl_xor(s1[r], 4, 64); s2[r] += __shfl_xor(s2[r], 4, 64);
    s1[r] += __shfl_xor(s1[r], 8, 64); s2[r] += __shfl_xor(s2[r], 8, 64);
  }
  const float bb1 = b1[0], bb2 = b2[0];
  if (m == 0) {
#pragma unroll
    for (int r = 0; r < 4; ++r) {
      a1[r0 + q * 4 + r] = s1[r] + bb1;
      a2[r0 + q * 4 + r] = s2[r] + bb2;
    }
  }
  float am = fmaxf(fmaxf(s2[0], s2[1]), fmaxf(s2[2], s2[3])) + bb2;
  am = fmaxf(am, __shfl_xor(am, 16, 64));
  am = fmaxf(am, __shfl_xor(am, 32, 64));
  if (lane == 0) {
    unsigned int u = __float_as_uint(am);
    unsigned int key = (u & 0x80000000u) ? ~u : (u | 0x80000000u);  // order-preserving
    atomicMax(a2key, key);
  }
}

// ---- Kernel 2 (MFMA, j-split x4): partial P@H + partial Z per slice ----------
// Grid 2048: bid -> (row-group, j-slice). 16 rows x 128 d x 2048 j per block,
// 16 tiles of 128 j. 8 blocks/CU (~32 waves/CU) vs the old 2: the barrier-
// separated per-tile latency chain (measured 2.8 us/tile, NOT BW-bound:
// VALUBusy 11.5%, hbm 10% cold / 0.3% warm at SAME duration) now overlaps
// 4x across blocks AND is 4x shorter per block.
__global__ __launch_bounds__(256) void GATLayer_46024869544127_kernel(
    const int* __restrict__ adj, const unsigned short* __restrict__ hT,
    const float* __restrict__ a1, const float* __restrict__ a2,
    const unsigned int* __restrict__ a2key,
    float* __restrict__ pacc, float* __restrict__ pz)
{
  __shared__ unsigned short p_lds[2][16][PSTRIDE];
  __shared__ float zred[4][16];

  const int tid = threadIdx.x;
  const int lane = tid & 63;
  const int w = tid >> 6;                  // wave 0..3
  const int js = blockIdx.x & (NSLICE - 1);
  const int r0 = (blockIdx.x >> 2) * 16;
  const int jb = js * JSL;
  const int NT = JSL / 128;                // 16 tiles

  // phase-A mapping: thread -> (row, 8-j group)
  const int arow = tid & 15;
  const int ajg = tid >> 4;
  const float a1i = a1[r0 + arow];
  const unsigned int kraw = *a2key;
  const unsigned int mu = (kraw & 0x80000000u) ? (kraw ^ 0x80000000u) : ~kraw;
  const float yi = a1i + __uint_as_float(mu);
  const float mi = fmaxf(yi, 0.01f * yi);  // leaky monotonic -> valid softmax shift

  float zpart = 0.f;
  const int* adjRow = adj + (size_t)(r0 + arow) * NN + jb + ajg * 8;
  const float* a2p = a2 + jb + ajg * 8;

  // phase-B mapping
  const int m = lane & 15, q = lane >> 4;
  const int d0 = w * 32;
  const unsigned short* hT0 = hT + (size_t)(d0 + m) * HS + q * 8;
  const unsigned short* hT1 = hT + (size_t)(d0 + 16 + m) * HS + q * 8;

  f32x4 acc0 = {}, acc1 = {};

  // pending regs for the NEXT tile's exp (named scalars -> VGPRs)
  int4v pd0, pd1;
  f32x4 pv0, pv1;

  auto issue = [&](int j0) {
    pd0 = *(const int4v*)(adjRow + j0);
    pd1 = *(const int4v*)(adjRow + j0 + 4);
    pv0 = *(const f32x4*)(a2p + j0);
    pv1 = *(const f32x4*)(a2p + j0 + 4);
  };
  auto expify = [&](ushort4v& o0, ushort4v& o1) {
#pragma unroll
    for (int t = 0; t < 4; ++t) {
      float y = a1i + pv0[t];
      float ly = fmaxf(y, 0.01f * y);
      float pv = (pd0[t] > 0) ? __expf(ly - mi) : 0.f;
      zpart += pv;
      o0[t] = f2bf(pv);
    }
#pragma unroll
    for (int t = 0; t < 4; ++t) {
      float y = a1i + pv1[t];
      float ly = fmaxf(y, 0.01f * y);
      float pv = (pd1[t] > 0) ? __expf(ly - mi) : 0.f;
      zpart += pv;
      o1[t] = f2bf(pv);
    }
  };

  // prologue: tile 0 -> LDS buf0 (synchronous once); issue tile 1 loads
  {
    issue(0);
    ushort4v o0, o1;
    expify(o0, o1);
    *(ushort4v*)&p_lds[0][arow][ajg * 8] = o0;
    *(ushort4v*)&p_lds[0][arow][ajg * 8 + 4] = o1;
  }
  issue(128);
  BAR_LDS();

  for (int jt = 0; jt < NT; ++jt) {
    const int cur = jt & 1;
    const int j0 = jb + jt * 128;          // global j for hT
    const bool hasN = (jt + 1) < NT;

    // B-frags for THIS tile
    const short8 b00 = *(const short8*)(hT0 + j0);
    const short8 b01 = *(const short8*)(hT1 + j0);
    const short8 b10 = *(const short8*)(hT0 + j0 + 32);
    const short8 b11 = *(const short8*)(hT1 + j0 + 32);
    const short8 b20 = *(const short8*)(hT0 + j0 + 64);
    const short8 b21 = *(const short8*)(hT1 + j0 + 64);
    const short8 b30 = *(const short8*)(hT0 + j0 + 96);
    const short8 b31 = *(const short8*)(hT1 + j0 + 96);

    // exp tile jt+1 from pending regs (issued one body ago)
    ushort4v o0, o1;
    if (hasN) expify(o0, o1);

    // issue adj/a2 loads for tile jt+2
    if (jt + 2 < NT) issue((jt + 2) * 128);

    // A-frags from LDS + 8 MFMAs over tile jt
    const short8 af0 = *(const short8*)&p_lds[cur][m][q * 8];
    const short8 af1 = *(const short8*)&p_lds[cur][m][32 + q * 8];
    const short8 af2 = *(const short8*)&p_lds[cur][m][64 + q * 8];
    const short8 af3 = *(const short8*)&p_lds[cur][m][96 + q * 8];
    acc0 = __builtin_amdgcn_mfma_f32_16x16x32_bf16(as_bf(af0), as_bf(b00), acc0, 0, 0, 0);
    acc1 = __builtin_amdgcn_mfma_f32_16x16x32_bf16(as_bf(af0), as_bf(b01), acc1, 0, 0, 0);
    acc0 = __builtin_amdgcn_mfma_f32_16x16x32_bf16(as_bf(af1), as_bf(b10), acc0, 0, 0, 0);
    acc1 = __builtin_amdgcn_mfma_f32_16x16x32_bf16(as_bf(af1), as_bf(b11), acc1, 0, 0, 0);
    acc0 = __builtin_amdgcn_mfma_f32_16x16x32_bf16(as_bf(af2), as_bf(b20), acc0, 0, 0, 0);
    acc1 = __builtin_amdgcn_mfma_f32_16x16x32_bf16(as_bf(af2), as_bf(b21), acc1, 0, 0, 0);
    acc0 = __builtin_amdgcn_mfma_f32_16x16x32_bf16(as_bf(af3), as_bf(b30), acc0, 0, 0, 0);
    acc1 = __builtin_amdgcn_mfma_f32_16x16x32_bf16(as_bf(af3), as_bf(b31), acc1, 0, 0, 0);

    // publish p(jt+1) into the other LDS buffer
    if (hasN) {
      *(ushort4v*)&p_lds[cur ^ 1][arow][ajg * 8] = o0;
      *(ushort4v*)&p_lds[cur ^ 1][arow][ajg * 8 + 4] = o1;
    }
    BAR_LDS();
  }

  // partial-Z reduction for this slice
  float zw = zpart;
  zw += __shfl_xor(zw, 16, 64);
  zw += __shfl_xor(zw, 32, 64);
  if (lane < 16) zred[w][arow] = zw;
  __syncthreads();

  if (tid < 16) {
    pz[(size_t)js * NN + r0 + tid] =
        zred[0][tid] + zred[1][tid] + zred[2][tid] + zred[3][tid];
  }
#pragma unroll
  for (int r = 0; r < 4; ++r) {
    const int row = q * 4 + r;
    float* po = pacc + (size_t)js * NN * DOUT + (size_t)(r0 + row) * DOUT + d0;
    po[m] = acc0[r];
    po[16 + m] = acc1[r];
  }
}

// ---- Kernel 3: combine 4 partial slices, normalize by summed Z ---------------
__global__ __launch_bounds__(256) void k3_combine(
    const float* __restrict__ pacc, const float* __restrict__ pz,
    float* __restrict__ out)
{
  const int v = blockIdx.x * 256 + threadIdx.x;   // f32x4 index over NN*DOUT/4
  const int idx = v * 4;
  const int i = idx >> 7;                         // row (DOUT=128)
  const size_t S = (size_t)NN * DOUT;
  f32x4 s0 = *(const f32x4*)(pacc + idx);
  f32x4 s1 = *(const f32x4*)(pacc + S + idx);
  f32x4 s2 = *(const f32x4*)(pacc + 2 * S + idx);
  f32x4 s3 = *(const f32x4*)(pacc + 3 * S + idx);
  const float Z = pz[i] + pz[NN + i] + pz[2 * NN + i] + pz[3 * NN + i];
  const float inv = (Z > 0.f) ? 1.f / Z : 0.f;
  f32x4 o;
#pragma unroll
  for (int t = 0; t < 4; ++t) o[t] = (s0[t] + s1[t] + s2[t] + s3[t]) * inv;
  *(f32x4*)(out + idx) = o;
}

extern "C" void kernel_launch(void* const* d_in, const int* in_sizes, int n_in,
                              void* d_out, int out_size, void* d_ws, size_t ws_size,
                              hipStream_t stream) {
  const float* feat = (const float*)d_in[0];
  const int* adj = (const int*)d_in[1];
  const float* W = (const float*)d_in[2];
  const float* b = (const float*)d_in[3];
  const float* w1 = (const float*)d_in[4];
  const float* b1 = (const float*)d_in[5];
  const float* w2 = (const float*)d_in[6];
  const float* b2 = (const float*)d_in[7];
  float* out = (float*)d_out;

  char* ws = (char*)d_ws;
  unsigned short* hT = (unsigned short*)ws;                 // 128*8208*2 B = 2,101,248
  size_t off = (size_t)DOUT * HS * 2;
  float* a1 = (float*)(ws + off);            off += (size_t)NN * 4;
  float* a2 = (float*)(ws + off);            off += (size_t)NN * 4;
  unsigned int* a2key = (unsigned int*)(ws + off); off += 256;     // keep alignment
  unsigned short* Wbf = (unsigned short*)(ws + off); off += (size_t)DOUT * DIN * 2;
  float* pacc = (float*)(ws + off);          off += (size_t)NSLICE * NN * DOUT * 4;
  float* pz   = (float*)(ws + off);          off += (size_t)NSLICE * NN * 4;

  k0_prep<<<DOUT * DIN / (256 * 4), 256, 0, stream>>>(W, Wbf, a2key);
  k1_h<<<512, 64, 0, stream>>>(feat, Wbf, b, w1, b1, w2, b2, hT, a1, a2, a2key);
  GATLayer_46024869544127_kernel<<<(NN / 16) * NSLICE, 256, 0, stream>>>(
      adj, hT, a1, a2, a2key, pacc, pz);
  k3_combine<<<NN * DOUT / (256 * 4), 256, 0, stream>>>(pacc, pz, out);
}